// Round 1
// 448.213 us; speedup vs baseline: 1.1691x; 1.1691x over previous
//
#include <hip/hip_runtime.h>
#include <cstdint>

// Attention block: x(B=64,T=128,C=2048) fp32; H=16, hd=128.
// q=x@wq^T, k=x@wk^T, v=x@wv^T ; RoPE(q,k) ; causal softmax attn ; out@wo^T.
// bf16 MFMA; fp32 softmax; RoPE fused into attention kernel.
// R4: GEMMs ported to 256x256 / BK=64 / 8-wave 8-phase counted-vmcnt schedule
//     (T3+T4) with setprio around MFMA clusters (T5); XOR granule swizzle kept (T2).

typedef unsigned short ushort;
typedef __bf16 bf16x8 __attribute__((ext_vector_type(8)));
typedef float floatx4 __attribute__((ext_vector_type(4)));

__device__ __forceinline__ ushort f2bf(float f) {
  union { float f; uint32_t u; } v; v.f = f;
  uint32_t r = v.u + 0x7FFFu + ((v.u >> 16) & 1u);
  return (ushort)(r >> 16);
}
__device__ __forceinline__ float bf2f(ushort h) {
  union { uint32_t u; float f; } v; v.u = ((uint32_t)h) << 16;
  return v.f;
}

__device__ __forceinline__ void load_lds16(const void* g, void* l) {
  __builtin_amdgcn_global_load_lds(
      (__attribute__((address_space(1))) void*)(uintptr_t)g,
      (__attribute__((address_space(3))) void*)(uint32_t)(uintptr_t)l,
      16, 0, 0);
}

__device__ __forceinline__ void store_out(ushort* C, size_t i, float v) { C[i] = f2bf(v); }
__device__ __forceinline__ void store_out(float* C, size_t i, float v) { C[i] = v; }

__device__ __forceinline__ void phase_mid() {
  __builtin_amdgcn_s_barrier();
  asm volatile("s_waitcnt lgkmcnt(0)" ::: "memory");
  __builtin_amdgcn_sched_barrier(0);
}
__device__ __forceinline__ void phase_end() {
  __builtin_amdgcn_s_barrier();
  __builtin_amdgcn_sched_barrier(0);
}

// C[m,n] = sum_k A[m,k]*B[n,k].
// 256x256 tile, BK=64, 512 threads (8 waves, 2M x 4N), per-wave 128x64 output.
// LDS: 2 dbuf x (A 256x64 + B 256x64) bf16 = 128 KiB, 1 block/CU.
// LDS tile row = 64 elems = 8 k-groups of 16B; slot (row,g) holds global k-group
// g ^ (row&7) (involution; staging pre-swizzles the GLOBAL source column so the
// linear global_load_lds destination works — rule #21).
// Schedule (per iter = 2 K-tiles, 8 phases):
//  ph1: read B-all+A-lo(buf0); stage As1.h1(kt=2i+1); MFMA lo.ks0
//  ph2:                        stage Bs0.h0(s0);      MFMA lo.ks1
//  ph3: read A-hi(buf0);       stage Bs0.h1(s0);      MFMA hi.ks0
//  ph4:                        stage As0.h0(s0); vmcnt(6); MFMA hi.ks1
//  ph5..ph8: mirror on buf1, staging s0.Ah1 then s1 B halves + s1.Ah0; vmcnt(6) at ph8.
// Every region staged in phase p was fully read (lgkmcnt(0)+barrier) by phase p-1.
// vmcnt(6) = 3 half-tiles (2 loads each) allowed in flight — never drain to 0 in loop.
template <typename OutT>
__device__ __forceinline__ void gemm256_body(const ushort* __restrict__ A,
                                             const ushort* __restrict__ B,
                                             OutT* __restrict__ C,
                                             int M, int N, int K) {
  (void)M;
  __shared__ __align__(16) ushort As[2][256 * 64];
  __shared__ __align__(16) ushort Bs[2][256 * 64];
  const int tid = threadIdx.x;
  const int wave = tid >> 6, lane = tid & 63;
  const int quad = lane >> 4, colv = lane & 15;
  const int wm = wave & 1, wn = wave >> 1;
  const int m0 = blockIdx.x * 256, n0 = blockIdx.y * 256;

  // Fragment read offsets (ushort units). Row r: r&7 == colv&7 (16-multiples drop out).
  const int a_base = (wm * 128 + colv) * 64;
  const int b_base = (wn * 64 + colv) * 64;
  const int kg0 = ((quad) ^ (colv & 7)) << 3;       // ks=0 granule, swizzled
  const int kg1 = ((quad | 4) ^ (colv & 7)) << 3;   // ks=1 granule, swizzled

  // Staging: thread tid covers LDS slot (row = L*64 + tid>>3, g = tid&7) per load L;
  // fetches global k-group g ^ (row&7)  (row&7 == (tid>>3)&7 for all halves/L).
  const int srow = tid >> 3;
  const int scol = ((tid & 7) ^ (srow & 7)) << 3;
  const ushort* Ag = A + (size_t)(m0 + srow) * K + scol;
  const ushort* Bg = B + (size_t)(n0 + srow) * K + scol;
  const int ldsw = wave * 512;

  floatx4 acc[8][4] = {};
  bf16x8 af[4][2], bfr[4][2];

#define STAGE(Gb, T, half, kt)                                             \
  {                                                                        \
    const ushort* g_ = (Gb) + (size_t)((half) * 128) * K + (kt) * 64;      \
    load_lds16(g_, &(T)[(half) * 8192 + ldsw]);                            \
    load_lds16(g_ + (size_t)64 * K, &(T)[(half) * 8192 + 4096 + ldsw]);    \
  }

#define READ_B_ALL(bi)                                                     \
  _Pragma("unroll") for (int nf = 0; nf < 4; ++nf) {                       \
    bfr[nf][0] = *(const bf16x8*)&Bs[bi][b_base + nf * 1024 + kg0];        \
    bfr[nf][1] = *(const bf16x8*)&Bs[bi][b_base + nf * 1024 + kg1];        \
  }

#define READ_A(bi, off)                                                    \
  _Pragma("unroll") for (int mf = 0; mf < 4; ++mf) {                       \
    af[mf][0] = *(const bf16x8*)&As[bi][a_base + (off) + mf * 1024 + kg0]; \
    af[mf][1] = *(const bf16x8*)&As[bi][a_base + (off) + mf * 1024 + kg1]; \
  }

#define MFMA16(ks, mo)                                                     \
  __builtin_amdgcn_s_setprio(1);                                           \
  _Pragma("unroll") for (int mf = 0; mf < 4; ++mf)                         \
  _Pragma("unroll") for (int nf = 0; nf < 4; ++nf)                         \
    acc[(mo) + mf][nf] = __builtin_amdgcn_mfma_f32_16x16x32_bf16(          \
        af[mf][(ks)], bfr[nf][(ks)], acc[(mo) + mf][nf], 0, 0, 0);         \
  __builtin_amdgcn_s_setprio(0);

  // Prologue: tile 0 complete (8 loads), then tile 1 B-halves + A-half0 (6 loads).
  STAGE(Bg, Bs[0], 0, 0)
  STAGE(Bg, Bs[0], 1, 0)
  STAGE(Ag, As[0], 0, 0)
  STAGE(Ag, As[0], 1, 0)
  STAGE(Bg, Bs[1], 0, 1)
  STAGE(Bg, Bs[1], 1, 1)
  STAGE(Ag, As[1], 0, 1)
  asm volatile("s_waitcnt vmcnt(6)" ::: "memory");  // oldest 8 (= tile 0) landed
  __builtin_amdgcn_s_barrier();
  __builtin_amdgcn_sched_barrier(0);

  const int NT = K >> 6;  // 32 K-tiles
#pragma unroll 1
  for (int it = 0; it < (NT >> 1); ++it) {
    const int s0 = (2 * it + 2 < NT) ? 2 * it + 2 : NT - 1;  // clamp: keep vmcnt counts uniform
    const int s1 = (2 * it + 3 < NT) ? 2 * it + 3 : NT - 1;

    // ---- ph1 (buf0: tile 2it) ----
    READ_B_ALL(0)
    READ_A(0, 0)
    STAGE(Ag, As[1], 1, 2 * it + 1)
    phase_mid();
    MFMA16(0, 0)
    phase_end();
    // ---- ph2 ----
    STAGE(Bg, Bs[0], 0, s0)
    phase_mid();
    MFMA16(1, 0)
    phase_end();
    // ---- ph3 ----
    READ_A(0, 4096)
    STAGE(Bg, Bs[0], 1, s0)
    phase_mid();
    MFMA16(0, 4)
    phase_end();
    // ---- ph4 ----
    STAGE(Ag, As[0], 0, s0)
    asm volatile("s_waitcnt vmcnt(6)" ::: "memory");  // buf1 (tile 2it+1) fully landed
    phase_mid();
    MFMA16(1, 4)
    phase_end();
    // ---- ph5 (buf1: tile 2it+1) ----
    READ_B_ALL(1)
    READ_A(1, 0)
    STAGE(Ag, As[0], 1, s0)
    phase_mid();
    MFMA16(0, 0)
    phase_end();
    // ---- ph6 ----
    STAGE(Bg, Bs[1], 0, s1)
    phase_mid();
    MFMA16(1, 0)
    phase_end();
    // ---- ph7 ----
    READ_A(1, 4096)
    STAGE(Bg, Bs[1], 1, s1)
    phase_mid();
    MFMA16(0, 4)
    phase_end();
    // ---- ph8 ----
    STAGE(Ag, As[1], 0, s1)
    asm volatile("s_waitcnt vmcnt(6)" ::: "memory");  // buf0 (tile 2it+2) fully landed
    phase_mid();
    MFMA16(1, 4)
    phase_end();
  }
  asm volatile("s_waitcnt vmcnt(0)" ::: "memory");  // drain tail stages before endpgm

#pragma unroll
  for (int mf = 0; mf < 8; ++mf)
#pragma unroll
    for (int nf = 0; nf < 4; ++nf)
#pragma unroll
      for (int r = 0; r < 4; ++r) {
        int m = m0 + wm * 128 + mf * 16 + quad * 4 + r;
        int n = n0 + wn * 64 + nf * 16 + colv;
        store_out(C, (size_t)m * N + n, acc[mf][nf][r]);
      }
#undef STAGE
#undef READ_B_ALL
#undef READ_A
#undef MFMA16
}

__global__ __launch_bounds__(512) void gemm_qkv(
    const ushort* __restrict__ A, const ushort* __restrict__ Wq,
    const ushort* __restrict__ Wk, const ushort* __restrict__ Wv,
    ushort* __restrict__ Q, ushort* __restrict__ Kb, ushort* __restrict__ V) {
  const ushort* B = (blockIdx.z == 0) ? Wq : (blockIdx.z == 1) ? Wk : Wv;
  ushort* C = (blockIdx.z == 0) ? Q : (blockIdx.z == 1) ? Kb : V;
  gemm256_body<ushort>(A, B, C, 8192, 2048, 2048);
}

__global__ __launch_bounds__(512) void gemm_out_k(
    const ushort* __restrict__ A, const ushort* __restrict__ B,
    float* __restrict__ C) {
  gemm256_body<float>(A, B, C, 8192, 2048, 2048);
}

// One kernel converting all five fp32 regions to bf16.
#define NX 4194304u   /* 8192*2048/4 */
#define NW 1048576u   /* 2048*2048/4 */
__global__ void cvt_all(const float* __restrict__ x, const float* __restrict__ wq,
                        const float* __restrict__ wk, const float* __restrict__ wv,
                        const float* __restrict__ wo,
                        ushort* __restrict__ xb, ushort* __restrict__ wqb,
                        ushort* __restrict__ wkb, ushort* __restrict__ wvb,
                        ushort* __restrict__ wob) {
  uint32_t i = blockIdx.x * 256u + threadIdx.x;
  const float* src;
  ushort* dst;
  uint32_t off;
  if (i < NX) {
    src = x; dst = xb; off = i;
  } else {
    uint32_t i2 = i - NX;
    uint32_t r = i2 >> 20;
    off = i2 & (NW - 1u);
    src = (r == 0) ? wq : (r == 1) ? wk : (r == 2) ? wv : wo;
    dst = (r == 0) ? wqb : (r == 1) ? wkb : (r == 2) ? wvb : wob;
  }
  float4 v = ((const float4*)src)[off];
  ushort4 o;
  o.x = f2bf(v.x); o.y = f2bf(v.y); o.z = f2bf(v.z); o.w = f2bf(v.w);
  ((ushort4*)dst)[off] = o;
}

// One block per (b,h). T=128, hd=128. RoPE applied to Q,K on load (fp32 math).
__global__ __launch_bounds__(256) void attn_kernel(
    const ushort* __restrict__ Q, const ushort* __restrict__ K,
    const ushort* __restrict__ V, const float* __restrict__ Cf,
    const float* __restrict__ Sf, ushort* __restrict__ O) {
  __shared__ __align__(16) ushort Qs[128 * 128];   // Q, then P
  __shared__ __align__(16) ushort KVs[128 * 128];  // K, then V^T
  const int b = blockIdx.x >> 4, h = blockIdx.x & 15;
  const int tid = threadIdx.x, wave = tid >> 6, lane = tid & 63;
  const int quad = lane >> 4, colv = lane & 15;
  const size_t gbase = (size_t)b * 262144 + (size_t)h * 128;

#pragma unroll
  for (int sgi = 0; sgi < 8; ++sgi) {
    int seg = tid + sgi * 256;
    int t = seg >> 4, g = seg & 15;
    uint4 qv = *(const uint4*)(Q + gbase + (size_t)t * 2048 + g * 8);
    uint4 kv = *(const uint4*)(K + gbase + (size_t)t * 2048 + g * 8);
    float4 cf = *(const float4*)(Cf + t * 64 + g * 4);
    float4 sf = *(const float4*)(Sf + t * 64 + g * 4);
    uint32_t* qw = (uint32_t*)&qv;
    uint32_t* kw = (uint32_t*)&kv;
#pragma unroll
    for (int j = 0; j < 4; ++j) {
      float c = (&cf.x)[j], s = (&sf.x)[j];
      uint32_t w = qw[j];
      float e = bf2f((ushort)(w & 0xFFFF)), o = bf2f((ushort)(w >> 16));
      qw[j] = (uint32_t)f2bf(e * c - o * s) | ((uint32_t)f2bf(e * s + o * c) << 16);
      w = kw[j];
      e = bf2f((ushort)(w & 0xFFFF)); o = bf2f((ushort)(w >> 16));
      kw[j] = (uint32_t)f2bf(e * c - o * s) | ((uint32_t)f2bf(e * s + o * c) << 16);
    }
    int so = t * 128 + ((g ^ (t & 15)) << 3);
    *(uint4*)&Qs[so] = qv;
    *(uint4*)&KVs[so] = kv;
  }
  __syncthreads();

  floatx4 accs[2][8] = {};
#pragma unroll
  for (int kc = 0; kc < 4; ++kc) {
    bf16x8 af[2], bfr[8];
#pragma unroll
    for (int i = 0; i < 2; ++i) {
      int r = wave * 32 + i * 16 + colv;
      af[i] = *(const bf16x8*)&Qs[r * 128 + ((((kc << 2) | quad) ^ (r & 15)) << 3)];
    }
#pragma unroll
    for (int j = 0; j < 8; ++j) {
      int r = j * 16 + colv;
      bfr[j] = *(const bf16x8*)&KVs[r * 128 + ((((kc << 2) | quad) ^ (r & 15)) << 3)];
    }
#pragma unroll
    for (int i = 0; i < 2; ++i)
#pragma unroll
      for (int j = 0; j < 8; ++j)
        accs[i][j] = __builtin_amdgcn_mfma_f32_16x16x32_bf16(af[i], bfr[j], accs[i][j], 0, 0, 0);
  }

  const float scale = 0.08838834764831845f;  // 1/sqrt(128)
#pragma unroll
  for (int i = 0; i < 2; ++i)
#pragma unroll
    for (int r = 0; r < 4; ++r) {
      int t = wave * 32 + i * 16 + quad * 4 + r;
      float mx = -1e30f;
#pragma unroll
      for (int j = 0; j < 8; ++j) {
        int s = j * 16 + colv;
        float v = accs[i][j][r] * scale;
        v = (s <= t) ? v : -1e30f;
        accs[i][j][r] = v;
        mx = fmaxf(mx, v);
      }
#pragma unroll
      for (int off = 1; off < 16; off <<= 1) mx = fmaxf(mx, __shfl_xor(mx, off, 64));
      float l = 0.f;
#pragma unroll
      for (int j = 0; j < 8; ++j) {
        float p = __expf(accs[i][j][r] - mx);
        accs[i][j][r] = p;
        l += p;
      }
#pragma unroll
      for (int off = 1; off < 16; off <<= 1) l += __shfl_xor(l, off, 64);
      float inv = 1.0f / l;
#pragma unroll
      for (int j = 0; j < 8; ++j) {
        int s = j * 16 + colv;
        Qs[t * 128 + ((((s >> 3) ^ (t & 15)) << 3) | (s & 7))] = f2bf(accs[i][j][r] * inv);
      }
    }
  __syncthreads();

#pragma unroll
  for (int sgi = 0; sgi < 8; ++sgi) {
    int seg = tid + sgi * 256;
    int t = seg >> 4;
    int dg = (seg & 15) << 3;
    uint4 vv = *(const uint4*)(V + gbase + (size_t)t * 2048 + dg);
    const ushort* vp = (const ushort*)&vv;
#pragma unroll
    for (int jj = 0; jj < 8; ++jj) {
      int d = dg + jj;
      KVs[d * 128 + ((((t >> 3) ^ (d & 15)) << 3) | (t & 7))] = vp[jj];
    }
  }
  __syncthreads();

  floatx4 acco[2][8] = {};
#pragma unroll
  for (int kc = 0; kc < 4; ++kc) {
    bf16x8 af[2], bfr[8];
#pragma unroll
    for (int i = 0; i < 2; ++i) {
      int r = wave * 32 + i * 16 + colv;
      af[i] = *(const bf16x8*)&Qs[r * 128 + ((((kc << 2) | quad) ^ (r & 15)) << 3)];
    }
#pragma unroll
    for (int j = 0; j < 8; ++j) {
      int r = j * 16 + colv;
      bfr[j] = *(const bf16x8*)&KVs[r * 128 + ((((kc << 2) | quad) ^ (r & 15)) << 3)];
    }
#pragma unroll
    for (int i = 0; i < 2; ++i)
#pragma unroll
      for (int j = 0; j < 8; ++j)
        acco[i][j] = __builtin_amdgcn_mfma_f32_16x16x32_bf16(af[i], bfr[j], acco[i][j], 0, 0, 0);
  }

#pragma unroll
  for (int i = 0; i < 2; ++i)
#pragma unroll
    for (int j = 0; j < 8; ++j)
#pragma unroll
      for (int r = 0; r < 4; ++r) {
        int t = wave * 32 + i * 16 + quad * 4 + r;
        int d = j * 16 + colv;
        O[gbase + (size_t)t * 2048 + d] = f2bf(acco[i][j][r]);
      }
}

extern "C" void kernel_launch(void* const* d_in, const int* in_sizes, int n_in,
                              void* d_out, int out_size, void* d_ws, size_t ws_size,
                              hipStream_t stream) {
  const float* x    = (const float*)d_in[0];
  const float* fcos = (const float*)d_in[1];
  const float* fsin = (const float*)d_in[2];
  const float* wq   = (const float*)d_in[3];
  const float* wk   = (const float*)d_in[4];
  const float* wv   = (const float*)d_in[5];
  const float* wo   = (const float*)d_in[6];
  float* out = (float*)d_out;

  const size_t CC = 2048ull * 2048ull;
  const size_t MC = 8192ull * 2048ull;
  ushort* wob = (ushort*)d_ws;
  ushort* xb  = wob + CC;
  ushort* wqb = xb + MC;
  ushort* wkb = wqb + CC;
  ushort* wvb = wkb + CC;
  ushort* Qb  = wvb + CC;
  ushort* Kb  = Qb + MC;
  ushort* Vb  = Kb + MC;

  unsigned cvt_blocks = (unsigned)((MC + 4 * CC) / 4 / 256);
  cvt_all<<<dim3(cvt_blocks), 256, 0, stream>>>(x, wq, wk, wv, wo, xb, wqb, wkb, wvb, wob);

  gemm_qkv<<<dim3(32, 8, 3), 512, 0, stream>>>(xb, wqb, wkb, wvb, Qb, Kb, Vb);
  attn_kernel<<<dim3(1024), 256, 0, stream>>>(Qb, Kb, Vb, fcos, fsin, xb);
  gemm_out_k<<<dim3(32, 8), 512, 0, stream>>>(xb, wob, out);
}